// Round 2
// 366.444 us; speedup vs baseline: 1.0367x; 1.0367x over previous
//
#include <hip/hip_runtime.h>
#include <hip/hip_bf16.h>

typedef unsigned short u16;
typedef short bf16x8 __attribute__((ext_vector_type(8)));
typedef float f32x4 __attribute__((ext_vector_type(4)));

#define DM     1024
#define SEQ    4096
#define NBATCH 4
#define NWIN   31
#define NTOK   16384   // NBATCH*SEQ

__device__ __forceinline__ u16 f2b(float f) {
  union { float f; unsigned u; } x; x.f = f;
  unsigned r = (x.u + 0x7fffu + ((x.u >> 16) & 1u)) >> 16;  // RNE
  return (u16)r;
}
__device__ __forceinline__ float b2f(u16 v) {
  union { unsigned u; float f; } x; x.u = ((unsigned)v) << 16; return x.f;
}
// async global->LDS, 16B per lane. lds dest is wave-uniform base + lane*16.
__device__ __forceinline__ void gload_lds16(const u16* g, u16* l) {
  __builtin_amdgcn_global_load_lds(
      (const __attribute__((address_space(1))) void*)g,
      (__attribute__((address_space(3))) void*)l, 16, 0, 0);
}
// raw barrier with COMPILER memory fences (no hw waitcnt drain): prevents
// IR/MIR motion of LDS reads / global_load_lds across the rendezvous.
__device__ __forceinline__ void barrier_mf() {
  asm volatile("" ::: "memory");
  __builtin_amdgcn_s_barrier();
  asm volatile("" ::: "memory");
}

// ---------------- fp32 -> bf16 convert (x4 vectorized) ----------------
__global__ __launch_bounds__(256) void k_convert(const float* __restrict__ in,
                                                 u16* __restrict__ out, int n4) {
  int i = blockIdx.x * 256 + threadIdx.x;
  if (i >= n4) return;
  float4 v = ((const float4*)in)[i];
  ushort4 o; o.x = f2b(v.x); o.y = f2b(v.y); o.z = f2b(v.z); o.w = f2b(v.w);
  ((ushort4*)out)[i] = o;
}

// ---------------- 4x W (K x N fp32) -> Wt (N x K bf16), fused ----------------
__global__ __launch_bounds__(256) void k_transpose4(const float* __restrict__ W0,
                                                    const float* __restrict__ W1,
                                                    const float* __restrict__ W2,
                                                    const float* __restrict__ W3,
                                                    u16* __restrict__ Wt) {
  __shared__ float tile[32][33];
  int z = blockIdx.z;
  const float* W = (z == 0) ? W0 : (z == 1) ? W1 : (z == 2) ? W2 : W3;
  u16* dst = Wt + (size_t)z * DM * DM;
  int n0 = blockIdx.x * 32, k0 = blockIdx.y * 32;
  int tx = threadIdx.x, ty = threadIdx.y;
  #pragma unroll
  for (int i = ty; i < 32; i += 8) tile[i][tx] = W[(size_t)(k0 + i) * DM + n0 + tx];
  __syncthreads();
  #pragma unroll
  for (int i = ty; i < 32; i += 8) dst[(size_t)(n0 + i) * DM + k0 + tx] = f2b(tile[tx][i]);
}

// ---------------- concat bias [bq|bk|bv] -> 3072 ----------------
__global__ __launch_bounds__(256) void k_catbias(const float* __restrict__ bq,
                                                 const float* __restrict__ bk,
                                                 const float* __restrict__ bv,
                                                 float* __restrict__ o) {
  int i = blockIdx.x * 256 + threadIdx.x;
  if (i >= 3 * DM) return;
  float v = (i < DM) ? bq[i] : (i < 2 * DM) ? bk[i - DM] : bv[i - 2 * DM];
  o[i] = v;
}

// ---------------- bf16 MFMA GEMM: C[M,N] = A[M,K] * Bt[N,K]^T + bias ----------------
// 256x256 tile, 8 waves (2M x 4N), per-wave 128x64 output, BK=64.
// 8-phase schedule (T3+T4+T5). Per-K-tile 4 phases, each:
//   {ds_reads, stage 1 half, barrier, setprio-wrapped MFMA quadrant, barrier}.
// TRUE last-read phases per STAGING half (each wave reads only its own halves):
//   A-half h: read p0 (a0, rows 0-63) and p1 (a1, rows 64-127) by wm==h waves
//   B-half h: read p0 (b0, cols 0-31) and p2 (b1, cols 32-63) by wn>>1==h waves
// => legal stage slots: p0->B1(t+1) [other buf], p1->A1(t+1) [other buf],
//    p2->A0(t+2) [live buf, A last read p1], p3->B0(t+2) [live buf, B last read p2].
// Issue stream per tile: [A0,B0,B1,A1]; steady outstanding at p3-end = 6 halves
// = 12 loads; vmcnt(4) drains exactly tile t+1 (all 4 halves read at p0 of t+1).
// Round-1 bug: B0(t+2) staged at p1 raced the p2 read of B0(t) -> absmax 1.39.
// LDS 128 KiB -> 1 block/CU (8 waves). Chunk-XOR swizzle unchanged (0-conflict).
// Requires K >= 128 (nkt >= 2); both call sites use K=1024.
__global__ __launch_bounds__(512, 2) void k_gemm(const u16* __restrict__ A, const u16* __restrict__ Bt,
                                                 const float* __restrict__ bias,
                                                 float* __restrict__ Cf,
                                                 u16* __restrict__ Cb, int ldc,
                                                 u16* __restrict__ Ct, int csplit,
                                                 int M, int N, int K) {
  __shared__ u16 As[32768];   // [buf 2][half 2][128][64]
  __shared__ u16 Bs[32768];
  const int tid = threadIdx.x;
  const int wv = tid >> 6, lane = tid & 63;
  const int quad = lane >> 4, l16 = lane & 15;
  const int lr8 = lane >> 3;                       // staging: row within 8-row issue
  const int lc8 = (((lane & 7) ^ (lr8 & 7)) * 8);  // staging: swizzled chunk
  const int k7 = l16 & 7;                          // frag-read swizzle key

  // XCD-aware bijective swizzle (nwg % 8 == 0 for both call sites)
  const int nwg = gridDim.x * gridDim.y;
  const int orig = blockIdx.y * gridDim.x + blockIdx.x;
  const int swz = (orig & 7) * (nwg >> 3) + (orig >> 3);
  const int m0 = (swz / gridDim.x) * 256;
  const int n0 = (swz % gridDim.x) * 256;
  const int wm = wv >> 2, wn = wv & 3;             // wave grid 2 x 4

  f32x4 acc[8][4];
  #pragma unroll
  for (int a = 0; a < 8; ++a)
    #pragma unroll
    for (int b = 0; b < 4; ++b) acc[a][b] = (f32x4){0.f, 0.f, 0.f, 0.f};

  const int nkt = K >> 6;          // 64-wide K-tiles
  const int send = nkt << 2;       // half stream length

  // stage half stream[s]: tile ts = s>>2, kind s&3 in [A0, B0, B1, A1]
  auto STG = [&](int s) {
    if (s >= send) return;
    const int ts = s >> 2, kd = s & 3;
    const int cb = (ts & 1) << 14;     // buffer offset in u16
    const int kk = ts << 6;
    #pragma unroll
    for (int j = 0; j < 2; ++j) {
      int e = wv * 2 + j;              // 16 issues cover 128 rows
      int row = e * 8 + lr8;
      if (kd == 0 || kd == 3) {        // A halves: kd0 -> h0, kd3 -> h1
        int h = (kd == 3);
        gload_lds16(A + (size_t)(m0 + h * 128 + row) * K + kk + lc8,
                    As + cb + h * 8192 + e * 512);
      } else {                         // B halves: kd1 -> h0, kd2 -> h1
        int h = (kd == 2);
        gload_lds16(Bt + (size_t)(n0 + h * 128 + row) * K + kk + lc8,
                    Bs + cb + h * 8192 + e * 512);
      }
    }
  };

  // ---- prologue: tile0 all 4 halves + A0(1), B0(1); land tile0 ----
  #pragma unroll
  for (int s = 0; s < 6; ++s) STG(s);
  asm volatile("s_waitcnt vmcnt(4)" ::: "memory");
  barrier_mf();

  for (int t = 0; t < nkt; ++t) {
    const int cb = (t & 1) << 14;
    const u16* Aw = As + cb + wm * 8192;          // this wave's A half
    const u16* Bw = Bs + cb + (wn >> 1) * 8192;   // this wave's B half
    const int bcol = (wn & 1) * 64;
    bf16x8 a0[8], a1[8], b0[4], b1[4];

    auto rdA = [&](bf16x8* d, int mh) {
      #pragma unroll
      for (int tt = 0; tt < 4; ++tt)
        #pragma unroll
        for (int s2 = 0; s2 < 2; ++s2)
          d[tt * 2 + s2] = *(const bf16x8*)&Aw[(mh * 64 + tt * 16 + l16) * 64 +
                                               (((s2 * 4 + quad) ^ k7) * 8)];
    };
    auto rdB = [&](bf16x8* d, int nh) {
      #pragma unroll
      for (int u = 0; u < 2; ++u)
        #pragma unroll
        for (int s2 = 0; s2 < 2; ++s2)
          d[u * 2 + s2] = *(const bf16x8*)&Bw[(bcol + nh * 32 + u * 16 + l16) * 64 +
                                              (((s2 * 4 + quad) ^ k7) * 8)];
    };
    auto MF = [&](const bf16x8* a, const bf16x8* b, int mh, int nh) {
      __builtin_amdgcn_s_setprio(1);
      #pragma unroll
      for (int s2 = 0; s2 < 2; ++s2)
        #pragma unroll
        for (int tt = 0; tt < 4; ++tt)
          #pragma unroll
          for (int u = 0; u < 2; ++u)
            acc[mh * 4 + tt][nh * 2 + u] = __builtin_amdgcn_mfma_f32_16x16x32_bf16(
                a[tt * 2 + s2], b[u * 2 + s2], acc[mh * 4 + tt][nh * 2 + u], 0, 0, 0);
      __builtin_amdgcn_s_setprio(0);
    };

    // phase 0: reads a0+b0 (12 ds_read_b128); stage B1(t+1) [other buffer]
    rdA(a0, 0); rdB(b0, 0);
    STG(4 * (t + 1) + 2);
    barrier_mf();
    MF(a0, b0, 0, 0);
    barrier_mf();
    // phase 1: reads a1 (8); stage A1(t+1) [other buffer]
    rdA(a1, 1);
    STG(4 * (t + 1) + 3);
    barrier_mf();
    MF(a1, b0, 1, 0);
    barrier_mf();
    // phase 2: reads b1 (4); stage A0(t+2) [live buffer; A last read p1]
    rdB(b1, 1);
    STG(4 * (t + 2) + 0);
    barrier_mf();
    MF(a0, b1, 0, 1);
    barrier_mf();
    // phase 3: no reads; stage B0(t+2) [live buffer; B last read p2]
    STG(4 * (t + 2) + 1);
    barrier_mf();
    MF(a1, b1, 1, 1);
    if (t < nkt - 2)       asm volatile("s_waitcnt vmcnt(4)" ::: "memory");
    else if (t == nkt - 2) asm volatile("s_waitcnt vmcnt(0)" ::: "memory");
    barrier_mf();
  }

  // ---- epilogue ----
  #pragma unroll
  for (int am = 0; am < 8; ++am) {
    #pragma unroll
    for (int an = 0; an < 4; ++an) {
      int row = m0 + wm * 128 + am * 16 + quad * 4;  // D: row=(lane>>4)*4+reg
      int col = n0 + wn * 64 + an * 16 + l16;        //    col=lane&15
      float bv = bias[col];
      if (Cf) {
        #pragma unroll
        for (int r = 0; r < 4; ++r)
          Cf[(size_t)(row + r) * N + col] = acc[am][an][r] + bv;
      } else if (col < csplit) {
        #pragma unroll
        for (int r = 0; r < 4; ++r)
          Cb[(size_t)(row + r) * ldc + col] = f2b(acc[am][an][r] + bv);
      } else {
        ushort4 o;
        o.x = f2b(acc[am][an][0] + bv); o.y = f2b(acc[am][an][1] + bv);
        o.z = f2b(acc[am][an][2] + bv); o.w = f2b(acc[am][an][3] + bv);
        *(ushort4*)&Ct[(size_t)(col - csplit) * M + row] = o;
      }
    }
  }
}

// ---------------- windowed attention ----------------
// Flat grid 512, XCD-swizzled; block 256 = 4 waves; LDS 74 KB -> 2 blocks/CU.
// Phase 1: S = Q*K^T/8, wave owns a 64-key slab for all 64 q, BK=64.
// Softmax: in-wave shfl + cross-wave LDS combine.
// Phase 2: O = P*V via Vt [d][tok]; parity-buffer stores (no atomics).
#define LDQ  2048
__global__ __launch_bounds__(256, 2) void k_attn(const u16* __restrict__ QKb, const u16* __restrict__ Vt,
                                                 u16* __restrict__ oA, u16* __restrict__ oB) {
  __shared__ u16 stage[20480];     // Qs 64x64 (8KB) + Ks 256x64 (32KB); reused as Vs 256x64
  __shared__ u16 Pbuf[64 * 256];   // 32KB
  __shared__ float red[2][4][64];  // cross-wave softmax partials (max, sum)
  u16* Qs = stage;
  u16* Ks = stage + 4096;
  u16* Vs = stage;

  const int tid = threadIdx.x;
  const int wv = tid >> 6, lane = tid & 63;
  const int quad = lane >> 4, l16 = lane & 15;
  const int l7 = lane & 7, lr8 = lane >> 3;
  const int kq = (l16 & 7) + (l16 >> 3);           // frag key base (rows = 16t + l16)

  // decode swizzled flat grid: id = (pair&7) + 8*(qt + 4*(pair>>3)), pair = w + 31*b
  int id = blockIdx.x;
  int s_ = id >> 3;
  int qt = s_ & 3;
  int pair = (s_ >> 2) * 8 + (id & 7);
  if (pair >= NWIN * NBATCH) return;
  int b = pair / NWIN, w = pair - NWIN * b;

  const int s0 = w * 128;
  const size_t base2 = (size_t)b * SEQ * LDQ;
  const size_t base  = (size_t)b * SEQ * DM;
  const size_t btok  = (size_t)b * SEQ;
  const int qrow0 = s0 + qt * 64;

  f32x4 acc[4][4];   // S[q = mt*16+quad*4+r][key = wv*64 + nt*16 + l16]
  #pragma unroll
  for (int mt = 0; mt < 4; ++mt)
    #pragma unroll
    for (int nt = 0; nt < 4; ++nt) acc[mt][nt] = (f32x4){0.f, 0.f, 0.f, 0.f};

  // ---- phase 1: scores, BK=64 ----
  for (int kk = 0; kk < DM; kk += 64) {
    #pragma unroll
    for (int j = 0; j < 10; ++j) {   // 40 issues: 8 Q + 32 K
      int idx = wv * 10 + j;
      if (idx < 8) {
        int lc = (l7 ^ ((lr8 + idx) & 7)) * 8;
        gload_lds16(QKb + base2 + (size_t)(qrow0 + idx * 8 + lr8) * LDQ + kk + lc, Qs + idx * 512);
      } else {
        int f = idx - 8;
        int lc = (l7 ^ ((lr8 + f) & 7)) * 8;
        gload_lds16(QKb + DM + base2 + (size_t)(s0 + f * 8 + lr8) * LDQ + kk + lc, Ks + f * 512);
      }
    }
    __syncthreads();
    #pragma unroll
    for (int s2 = 0; s2 < 2; ++s2) {
      bf16x8 aq[4], bk[4];
      #pragma unroll
      for (int mt = 0; mt < 4; ++mt)
        aq[mt] = *(const bf16x8*)&Qs[(mt * 16 + l16) * 64 + (((s2 * 4 + quad) ^ ((kq + 2 * mt) & 7)) * 8)];
      #pragma unroll
      for (int nt = 0; nt < 4; ++nt)
        bk[nt] = *(const bf16x8*)&Ks[(wv * 64 + nt * 16 + l16) * 64 + (((s2 * 4 + quad) ^ ((kq + 2 * nt) & 7)) * 8)];
      #pragma unroll
      for (int mt = 0; mt < 4; ++mt)
        #pragma unroll
        for (int nt = 0; nt < 4; ++nt)
          acc[mt][nt] = __builtin_amdgcn_mfma_f32_16x16x32_bf16(aq[mt], bk[nt], acc[mt][nt], 0, 0, 0);
    }
    __syncthreads();
  }

  // ---- softmax over 256 keys ----
  float mx[4][4], sm[4][4];
  #pragma unroll
  for (int mt = 0; mt < 4; ++mt)
    #pragma unroll
    for (int r = 0; r < 4; ++r) mx[mt][r] = -1e30f;
  #pragma unroll
  for (int mt = 0; mt < 4; ++mt)
    #pragma unroll
    for (int nt = 0; nt < 4; ++nt)
      #pragma unroll
      for (int r = 0; r < 4; ++r) {
        float v = acc[mt][nt][r] * 0.125f;
        acc[mt][nt][r] = v;
        mx[mt][r] = fmaxf(mx[mt][r], v);
      }
  #pragma unroll
  for (int mt = 0; mt < 4; ++mt)
    #pragma unroll
    for (int r = 0; r < 4; ++r)
      #pragma unroll
      for (int off = 8; off > 0; off >>= 1)
        mx[mt][r] = fmaxf(mx[mt][r], __shfl_xor(mx[mt][r], off, 64));
  if (l16 == 0) {
    #pragma unroll
    for (int mt = 0; mt < 4; ++mt)
      #pragma unroll
      for (int r = 0; r < 4; ++r)
        red[0][wv][mt * 16 + quad * 4 + r] = mx[mt][r];
  }
  __syncthreads();
  float gm[4][4];
  #pragma unroll
  for (int mt = 0; mt < 4; ++mt)
    #pragma unroll
    for (int r = 0; r < 4; ++r) {
      int q = mt * 16 + quad * 4 + r;
      gm[mt][r] = fmaxf(fmaxf(red[0][0][q], red[0][1][q]), fmaxf(red[0][2][q], red[0][3][q]));
      sm[mt][r] = 0.f;
    }
  #pragma unroll
  for (int mt = 0; mt < 4; ++mt)
    #pragma unroll
    for (int nt = 0; nt < 4; ++nt)
      #pragma unroll
      for (int r = 0; r < 4; ++r) {
        float e = __expf(acc[mt][nt][r] - gm[mt][r]);
        acc[mt][nt][r] = e;
        sm[mt][r] += e;
      }
  #pragma unroll
  for (int mt = 0; mt < 4; ++mt)
    #pragma unroll
    for (int r = 0; r < 4; ++r)
      #pragma unroll
      for (int off = 8; off > 0; off >>= 1)
        sm[mt][r] += __shfl_xor(sm[mt][r], off, 64);
  if (l16 == 0) {
    #pragma unroll
    for (int mt = 0; mt < 4; ++mt)
      #pragma unroll
      for (int r = 0; r < 4; ++r)
        red[1][wv][mt * 16 + quad * 4 + r] = sm[mt][r];
  }
  __syncthreads();
  // normalize and write P (chunk-swizzled by q&7)
  #pragma unroll
  for (int mt = 0; mt < 4; ++mt)
    #pragma unroll
    for (int r = 0; r < 4; ++r) {
      int q = mt * 16 + quad * 4 + r;
      float inv = 1.f / (red[1][0][q] + red[1][1][q] + red[1][2][q] + red[1][3][q]);
      #pragma unroll
      for (int nt = 0; nt < 4; ++nt) {
        int ke = wv * 64 + nt * 16 + l16;
        int phys = (ke >> 3) ^ (q & 7);
        Pbuf[q * 256 + phys * 8 + (ke & 7)] = f2b(acc[mt][nt][r] * inv);
      }
    }
  __syncthreads();

  // ---- phase 2: O = P * V (M=64, K=256, N=1024 in 4 slabs; 64-token V steps) ----
  u16* op = ((w & 1) ? oB : oA) + base;
  for (int slab = 0; slab < 4; ++slab) {
    const int nb = slab * 256;
    f32x4 acc2[4][4];   // [mt][u]: rows q, cols nb + wv*64 + u*16 + l16
    #pragma unroll
    for (int mt = 0; mt < 4; ++mt)
      #pragma unroll
      for (int u = 0; u < 4; ++u) acc2[mt][u] = (f32x4){0.f, 0.f, 0.f, 0.f};
    for (int sk = 0; sk < 4; ++sk) {
      const int tok0 = sk * 64;
      #pragma unroll
      for (int j = 0; j < 8; ++j) {      // 32 issues: 256 d-rows x 64 tokens
        int e = wv * 8 + j;
        int lc = (l7 ^ ((lr8 + e) & 7)) * 8;
        gload_lds16(Vt + (size_t)(nb + e * 8 + lr8) * NTOK + btok + s0 + tok0 + lc, Vs + e * 512);
      }
      __syncthreads();
      #pragma unroll
      for (int s2 = 0; s2 < 2; ++s2) {
        bf16x8 af[4];
        #pragma unroll
        for (int mt = 0; mt < 4; ++mt) {
          int cP = sk * 8 + s2 * 4 + quad;             // logical chunk in 0..31
          int phys = cP ^ (l16 & 7);
          af[mt] = *(const bf16x8*)&Pbuf[(mt * 16 + l16) * 256 + phys * 8];
        }
        #pragma unroll
        for (int u = 0; u < 4; ++u) {
          bf16x8 bb = *(const bf16x8*)&Vs[(wv * 64 + u * 16 + l16) * 64 +
                                          (((s2 * 4 + quad) ^ ((kq + 2 * u) & 7)) * 8)];
          #pragma unroll
          for (int mt = 0; mt < 4; ++mt)
            acc2[mt][u] = __builtin_amdgcn_mfma_f32_16x16x32_bf16(af[mt], bb, acc2[mt][u], 0, 0, 0);
        }
      }
      __syncthreads();
    }
    #pragma unroll
    for (int mt = 0; mt < 4; ++mt)
      #pragma unroll
      for (int u = 0; u < 4; ++u) {
        int row = qrow0 + mt * 16 + quad * 4;
        int col = nb + wv * 64 + u * 16 + l16;
        #pragma unroll
        for (int r = 0; r < 4; ++r)
          op[(size_t)(row + r) * DM + col] = f2b(acc2[mt][u][r]);
      }
  }
}

// ---------------- merge parity buffers -> bf16 (x8 vectorized) ----------------
__global__ __launch_bounds__(256) void k_norm(const u16* __restrict__ oA, const u16* __restrict__ oB,
                                              u16* __restrict__ out, int n8) {
  int i = blockIdx.x * 256 + threadIdx.x;
  if (i >= n8) return;
  int s = (i >> 7) & (SEQ - 1);     // 128 groups of 8 per token row
  uint4 a = ((const uint4*)oA)[i];
  uint4 r = a;
  if (s >= 128 && s < 3968) {       // interior: one even + one odd window
    uint4 bq = ((const uint4*)oB)[i];
    const unsigned* ap = (const unsigned*)&a;
    const unsigned* bp = (const unsigned*)&bq;
    unsigned* rp = (unsigned*)&r;
    #pragma unroll
    for (int k = 0; k < 4; ++k) {
      float lo = 0.5f * (b2f((u16)(ap[k] & 0xffff)) + b2f((u16)(bp[k] & 0xffff)));
      float hi = 0.5f * (b2f((u16)(ap[k] >> 16))    + b2f((u16)(bp[k] >> 16)));
      rp[k] = (unsigned)f2b(lo) | ((unsigned)f2b(hi) << 16);
    }
  }
  ((uint4*)out)[i] = r;
}

extern "C" void kernel_launch(void* const* d_in, const int* in_sizes, int n_in,
                              void* d_out, int out_size, void* d_ws, size_t ws_size,
                              hipStream_t stream) {
  const float* x  = (const float*)d_in[0];
  const float* Wq = (const float*)d_in[1];
  const float* bq = (const float*)d_in[2];
  const float* Wk = (const float*)d_in[3];
  const float* bk = (const float*)d_in[4];
  const float* Wv = (const float*)d_in[5];
  const float* bv = (const float*)d_in[6];
  const float* Wo = (const float*)d_in[7];
  const float* bo = (const float*)d_in[8];
  float* out = (float*)d_out;

  char* ws = (char*)d_ws;
  const size_t MB = 1024 * 1024;
  u16*   xb   = (u16*)(ws);                 // 32 MB: x bf16; later merged attn output
  u16*   qkb  = (u16*)(ws + 32 * MB);       // 64 MB: [tok][2048] q|k
  u16*   vtb  = (u16*)(ws + 96 * MB);       // 32 MB: V transposed [d][tok]
  u16*   wqt  = (u16*)(ws + 128 * MB);      // 8 MB: wqt|wkt|wvt|wot contiguous
  float* bcat = (float*)(ws + 136 * MB);    // 12 KB
  u16*   oA   = (u16*)(ws + 137 * MB);      // 32 MB
  u16*   oB   = (u16*)(ws + 169 * MB);      // 32 MB  (end: 201 MB)

  int n4tok = (int)((size_t)NTOK * DM / 4);
  k_convert<<<(n4tok + 255) / 256, 256, 0, stream>>>(x, xb, n4tok);
  k_transpose4<<<dim3(DM / 32, DM / 32, 4), dim3(32, 8), 0, stream>>>(Wq, Wk, Wv, Wo, wqt);
  k_catbias<<<12, 256, 0, stream>>>(bq, bk, bv, bcat);

  // fused QKV GEMM: N=3072 over [wqt|wkt|wvt]; q,k -> qkb row-major; v -> vtb transposed
  k_gemm<<<dim3(3 * DM / 256, NTOK / 256), 512, 0, stream>>>(
      xb, wqt, bcat, nullptr, qkb, 2048, vtb, 2048, NTOK, 3 * DM, DM);

  k_attn<<<512, 256, 0, stream>>>(qkb, vtb, oA, oB);

  int n8tok = (int)((size_t)NTOK * DM / 8);
  k_norm<<<(n8tok + 255) / 256, 256, 0, stream>>>(oA, oB, xb, n8tok);

  u16* wot = wqt + 3 * (size_t)DM * DM;
  k_gemm<<<dim3(DM / 256, NTOK / 256), 512, 0, stream>>>(
      xb, wot, bo, out, nullptr, DM, nullptr, DM, NTOK, DM, DM);
}